// Round 7
// baseline (190.894 us; speedup 1.0000x reference)
//
#include <hip/hip_runtime.h>
#include <hip/hip_cooperative_groups.h>
#include <cstdint>

namespace cg = cooperative_groups;

// Problem constants (from reference)
#define DIMS   1100
#define NPOS   784          // 28*28
#define NLEV   256
#define BATCH  512
#define NW     25           // ceil(784/32) words of packed position bits
#define TROW   268          // padded words per w-row (16B aligned; 268%32==12 staggers banks)

// ---------------------------------------------------------------------------
// Fused cooperative kernel: 512 blocks x 256 threads (2 blocks/CU, 27.7KB LDS).
// Phase 1 (prep): blocks cover d = b, b+512, b+1024 -> t_arr[d], pbits[w][d]
//   via __ballot sign-packing (no serial load chains).
// __threadfence + grid.sync (device-scope visibility across XCDs).
// Phase 2 (encode): block b = batch element b:
//   scatter equality bits E[idx][w] into LDS -> suffix-OR scan U[t][w] ->
//   diff[d] = sum_w popc(pbits[w][d] ^ U[t(d)][w]); out = diff<392 ? +1 : -1.
// x is prefetched at kernel entry so its HBM latency hides under phase 1.
// ---------------------------------------------------------------------------
__global__ __launch_bounds__(256, 2) void fused_kernel(
    const float* __restrict__ x, const float* __restrict__ pos,
    const float* __restrict__ val, int* __restrict__ t_arr,
    uint32_t* __restrict__ pbits, float* __restrict__ out)
{
    __shared__ uint32_t U[NW * TROW];   // 25*268 words = 26.8 KB
    __shared__ uint32_t S[NW * 8];      // scan segment totals
    __shared__ int s4[4];               // per-wave popcounts (prep)

    const int tid  = threadIdx.x;
    const int b    = blockIdx.x;        // batch element AND prep stride base
    const int lane = tid & 63;
    const int wv   = tid >> 6;          // wave id 0..3

    // ---- early x prefetch: latency hides under all of phase 1 ----
    float4 xv = make_float4(0.f, 0.f, 0.f, 0.f);
    if (tid < NPOS / 4)
        xv = ((const float4*)x)[b * (NPOS / 4) + tid];

    // ---- zero U (no barrier needed before phase 1: U untouched there) ----
    uint4* U4 = (uint4*)U;
    #pragma unroll
    for (int i = 0; i < 7; ++i) {            // 7*256 = 1792 >= 25*268/4 = 1675
        int p = tid + i * 256;
        if (p < NW * TROW / 4) U4[p] = make_uint4(0u, 0u, 0u, 0u);
    }

    // ---- phase 1: prep columns d = b, b+512, b+1024 ----
    for (int d = b; d < DIMS; d += BATCH) {
        // t_arr: level l = tid (exactly 256 levels); count -1s per column
        bool neg = val[tid * DIMS + d] < 0.0f;
        unsigned long long m = __ballot(neg);
        if (lane == 0) s4[wv] = __popcll(m);

        // pbits: 4 passes over n = p*256 + tid, ballot-packed
        #pragma unroll
        for (int p = 0; p < 4; ++p) {
            int n = p * 256 + tid;
            bool bit = (n < NPOS) ? (pos[n * DIMS + d] > 0.0f) : false;
            unsigned long long mm = __ballot(bit);
            int w0 = p * 8 + wv * 2;
            if (lane == 0 && w0 < NW)      pbits[w0 * DIMS + d]       = (uint32_t)mm;
            if (lane == 32 && w0 + 1 < NW) pbits[(w0 + 1) * DIMS + d] = (uint32_t)(mm >> 32);
        }
        __syncthreads();
        if (tid == 0) t_arr[d] = s4[0] + s4[1] + s4[2] + s4[3];
        __syncthreads();                  // protect s4 reuse next iteration
    }

    // ---- device-scope visibility, then grid-wide barrier ----
    __threadfence();
    cg::this_grid().sync();

    // ---- prefetch thresholds (latency hides under scatter+scan) ----
    int td0[5];
    #pragma unroll
    for (int k = 0; k < 5; ++k) {
        int d = tid + (k << 8);
        td0[k] = (d < DIMS) ? t_arr[d] : 0;
    }

    // ---- scatter equality bits (x already in registers) ----
    if (tid < NPOS / 4) {
        float vv[4] = {xv.x, xv.y, xv.z, xv.w};
        #pragma unroll
        for (int j = 0; j < 4; ++j) {
            int n = tid * 4 + j;
            float v = fminf(fmaxf(vv[j] * (1.0f / 256.0f), 0.0f), 1.0f) * 255.0f;
            int idx = (int)rintf(v);         // round half to even, as jnp.round
            atomicOr(&U[(n >> 5) * TROW + idx], 1u << (n & 31));
        }
    }
    __syncthreads();

    // ---- suffix-OR scan: U[t] = OR_{l>=t} E[l]; 25 w-rows x 8 segments of 32 ----
    if (tid < NW * 8) {
        const int w = tid >> 3, seg = tid & 7;
        uint4* row4 = (uint4*)&U[w * TROW + seg * 32];
        uint32_t acc = 0;
        #pragma unroll
        for (int i = 7; i >= 0; --i) {       // reverse streaming RMW, ~5 live regs
            uint4 t = row4[i];
            uint32_t d3 = acc | t.w, d2 = d3 | t.z, d1 = d2 | t.y, d0 = d1 | t.x;
            row4[i] = make_uint4(d0, d1, d2, d3);
            acc = d0;
        }
        S[tid] = acc;
    }
    __syncthreads();
    if (tid < NW * 8) {
        const int w = tid >> 3, seg = tid & 7;
        uint32_t carry = 0;
        for (int s2 = seg + 1; s2 < 8; ++s2) carry |= S[(w << 3) + s2];
        if (carry) {
            uint4* row4 = (uint4*)&U[w * TROW + seg * 32];
            #pragma unroll
            for (int i = 0; i < 8; ++i) {
                uint4 r = row4[i];
                row4[i] = make_uint4(r.x | carry, r.y | carry, r.z | carry, r.w | carry);
            }
        }
    }
    __syncthreads();

    // ---- main: each thread covers d = tid + 256k ----
    #pragma unroll
    for (int k = 0; k < 5; ++k) {
        int d = tid + (k << 8);
        if (d < DIMS) {
            int t = td0[k];
            uint32_t diff = 0;
            #pragma unroll
            for (int ww = 0; ww < NW; ++ww) {
                uint32_t pb = pbits[ww * DIMS + d];   // coalesced, L2-resident
                uint32_t ub = U[ww * TROW + t];
                diff += __popc(pb ^ ub);
            }
            out[b * DIMS + d] = (diff < (NPOS / 2)) ? 1.0f : -1.0f;
        }
    }
}

// ---------------------------------------------------------------------------
extern "C" void kernel_launch(void* const* d_in, const int* in_sizes, int n_in,
                              void* d_out, int out_size, void* d_ws, size_t ws_size,
                              hipStream_t stream) {
    const float* x   = (const float*)d_in[0];   // (512, 28, 28)
    const float* pos = (const float*)d_in[1];   // (784, 1100)
    const float* val = (const float*)d_in[2];   // (256, 1100)
    float* out = (float*)d_out;                 // (512, 1100) float32

    // workspace: t_arr[1100] ints, then pbits[25][1100] words (16B-aligned offset)
    int* t_arr = (int*)d_ws;
    uint32_t* pbits = (uint32_t*)d_ws + 1104;

    void* args[] = {(void*)&x, (void*)&pos, (void*)&val,
                    (void*)&t_arr, (void*)&pbits, (void*)&out};
    hipLaunchCooperativeKernel(reinterpret_cast<void*>(fused_kernel),
                               dim3(BATCH), dim3(256), args, 0, stream);
}

// Round 10
// 76.647 us; speedup vs baseline: 2.4906x; 2.4906x over previous
//
#include <hip/hip_runtime.h>
#include <cstdint>

// Problem constants (from reference)
#define DIMS   1100
#define NPOS   784          // 28*28
#define NLEV   256
#define BATCH  512
#define NW     25           // ceil(784/32) words of packed position bits
#define UROW   28           // padded words per t-row of U (25 used; 28 -> 112B = 7x16B aligned)

// ---------------------------------------------------------------------------
// Prep kernel (ballot version, verbatim from round 6 / known-good):
//   t_arr[d] = count of -1s in thermometer column d  (V[l][d]==+1 iff l>=t)
//   pbits[w][d] = packed sign bits of position_weight column d
// ---------------------------------------------------------------------------
__global__ __launch_bounds__(256) void prep2_kernel(
    const float* __restrict__ pos, const float* __restrict__ val,
    int* __restrict__ t_arr, uint32_t* __restrict__ pbits)
{
    const int d    = blockIdx.x;       // 0..1099
    const int tid  = threadIdx.x;      // 0..255
    const int lane = tid & 63;
    const int wv   = tid >> 6;         // wave id 0..3
    __shared__ int s4[4];

    // ---- t_arr: level l = tid (exactly 256 levels) ----
    bool neg = val[tid * DIMS + d] < 0.0f;
    unsigned long long m = __ballot(neg);
    if (lane == 0) s4[wv] = __popcll(m);

    // ---- pbits: 4 passes over n = p*256 + tid ----
    #pragma unroll
    for (int p = 0; p < 4; ++p) {
        int n = p * 256 + tid;
        bool bit = (n < NPOS) ? (pos[n * DIMS + d] > 0.0f) : false;
        unsigned long long mm = __ballot(bit);
        int w0 = p * 8 + wv * 2;       // word covered by this wave's low half
        if (lane == 0 && w0 < NW)      pbits[w0 * DIMS + d]       = (uint32_t)mm;
        if (lane == 32 && w0 + 1 < NW) pbits[(w0 + 1) * DIMS + d] = (uint32_t)(mm >> 32);
    }

    __syncthreads();
    if (tid == 0) t_arr[d] = s4[0] + s4[1] + s4[2] + s4[3];
}

// ---------------------------------------------------------------------------
// Encode kernel: one block per batch element. U stored TRANSPOSED: U[t][w]
// with 28-word rows (112B, 16B-aligned) so the main-loop read of all 25 words
// for one t is 7x ds_read_b128 instead of 125x ds_read_b32.
//  1. scatter equality bits E at U[idx][w] (LDS atomicOr)
//  2. suffix-OR over t (per (w,seg): 32-step streaming RMW down column w)
//  3. per d: diff = popc over 25 words of (pbits[w][d] ^ U[t(d)][w]);
//     out = (diff < 392) ? +1 : -1    (s = 784 - 2*diff; s>0 <=> diff<392)
// ---------------------------------------------------------------------------
__global__ __launch_bounds__(256) void encode_kernel(
    const float* __restrict__ x, const int* __restrict__ t_arr,
    const uint32_t* __restrict__ pbits, float* __restrict__ out)
{
    __shared__ uint32_t U[NLEV * UROW];  // 256*28 words = 28 KB
    __shared__ uint32_t S[NW * 8];       // segment totals

    const int tid = threadIdx.x;
    const int b = blockIdx.x;

    // ---- prefetch thresholds early (hides global latency under LDS phases) ----
    int td0[5];
    #pragma unroll
    for (int k = 0; k < 5; ++k) {
        int d = tid + (k << 8);
        td0[k] = (d < DIMS) ? t_arr[d] : 0;
    }

    // ---- zero U (256*28/4 = 1792 = 7*256 uint4 stores) ----
    uint4* U4 = (uint4*)U;
    #pragma unroll
    for (int i = 0; i < 7; ++i)
        U4[tid + i * 256] = make_uint4(0u, 0u, 0u, 0u);
    __syncthreads();

    // ---- scatter equality bits (x as float4: 196 threads x 4 pixels) ----
    if (tid < NPOS / 4) {
        float4 xv = ((const float4*)x)[b * (NPOS / 4) + tid];
        float vv[4] = {xv.x, xv.y, xv.z, xv.w};
        #pragma unroll
        for (int j = 0; j < 4; ++j) {
            int n = tid * 4 + j;
            float v = fminf(fmaxf(vv[j] * (1.0f / 256.0f), 0.0f), 1.0f) * 255.0f;
            int idx = (int)rintf(v);         // round half to even, as jnp.round
            atomicOr(&U[idx * UROW + (n >> 5)], 1u << (n & 31));
        }
    }
    __syncthreads();

    // ---- suffix-OR over t: 200 lanes, (w,seg) = (tid%25, tid/25) so a wave's
    //      lanes span 25 distinct w -> <=3-way bank aliasing ----
    if (tid < NW * 8) {
        const int w = tid % 25, seg = tid / 25;     // seg 0..7
        uint32_t acc = 0;
        #pragma unroll
        for (int i = 31; i >= 0; --i) {             // t descending within segment
            int t = seg * 32 + i;
            acc |= U[t * UROW + w];
            U[t * UROW + w] = acc;
        }
        S[w * 8 + seg] = acc;
    }
    __syncthreads();
    if (tid < NW * 8) {
        const int w = tid % 25, seg = tid / 25;
        uint32_t carry = 0;
        for (int s2 = seg + 1; s2 < 8; ++s2) carry |= S[w * 8 + s2];
        if (carry) {
            #pragma unroll
            for (int i = 0; i < 32; ++i) {
                int t = seg * 32 + i;
                U[t * UROW + w] |= carry;
            }
        }
    }
    __syncthreads();

    // ---- main: each thread covers d = tid + 256k; 7x ds_read_b128 per d ----
    #pragma unroll
    for (int k = 0; k < 5; ++k) {
        int d = tid + (k << 8);
        if (d < DIMS) {
            int t = td0[k];
            const uint4* urow = (const uint4*)&U[t * UROW];   // 112B row, 16B-aligned
            uint32_t diff = 0;
            #pragma unroll
            for (int j = 0; j < 6; ++j) {
                uint4 u4 = urow[j];
                diff += __popc(u4.x ^ pbits[(4 * j + 0) * DIMS + d]);
                diff += __popc(u4.y ^ pbits[(4 * j + 1) * DIMS + d]);
                diff += __popc(u4.z ^ pbits[(4 * j + 2) * DIMS + d]);
                diff += __popc(u4.w ^ pbits[(4 * j + 3) * DIMS + d]);
            }
            diff += __popc(urow[6].x ^ pbits[24 * DIMS + d]); // w=24 (words 25..27 = pad)
            out[b * DIMS + d] = (diff < (NPOS / 2)) ? 1.0f : -1.0f;
        }
    }
}

// ---------------------------------------------------------------------------
extern "C" void kernel_launch(void* const* d_in, const int* in_sizes, int n_in,
                              void* d_out, int out_size, void* d_ws, size_t ws_size,
                              hipStream_t stream) {
    const float* x   = (const float*)d_in[0];   // (512, 28, 28)
    const float* pos = (const float*)d_in[1];   // (784, 1100)
    const float* val = (const float*)d_in[2];   // (256, 1100)
    float* out = (float*)d_out;                 // (512, 1100) float32

    // workspace: t_arr[1100] ints, then pbits[25][1100] words (16B-aligned offset)
    int* t_arr = (int*)d_ws;
    uint32_t* pbits = (uint32_t*)d_ws + 1104;

    prep2_kernel<<<DIMS, 256, 0, stream>>>(pos, val, t_arr, pbits);
    encode_kernel<<<BATCH, 256, 0, stream>>>(x, t_arr, pbits, out);
}